// Round 1
// baseline (761.545 us; speedup 1.0000x reference)
//
#include <hip/hip_runtime.h>
#include <hip/hip_bf16.h>

typedef __attribute__((ext_vector_type(8)))  short bf16x8_t;
typedef __attribute__((ext_vector_type(16))) float f32x16_t;
typedef __attribute__((ext_vector_type(4)))  float f32x4_t;

#define HN 10
#define BN 32768
#define DH 256
#define MT 128

// LDS layout (bytes)
#define SMEM_BYTES 138240
#define OFF_BUFA 0
#define OFF_BUFB 65536
#define OFF_S51  131072
#define OFF_S52  132096
#define OFF_W1S  133120
#define OFF_B1S  137216

// ws layout: packed bf16 weights
// wpk: [5 layer-arrays][10 heads][ks(16)][ntile(8)][lane(64)][8]  (65536 bf16 per (arr,head))
// w5pk: [2 branches][10 heads][ks(16)][lane(64)][8]               (8192 bf16 per (br,head))
#define WPK_ELEMS_PER_HEAD (DH*DH)
#define WPK_ELEMS_PER_ARR  (HN*DH*DH)
#define W5PK_ELEMS_PER_BH  8192

__device__ __forceinline__ unsigned swzoff(int row, int colb) {
  // row-major [128][256] bf16, 512 B/row, XOR-swizzled to break bank conflicts
  return (unsigned)(row * 512 + (colb ^ ((row & 7) << 4)));
}

__device__ __forceinline__ unsigned short f2bf(float v) {
  __hip_bfloat16 hb = __float2bfloat16(v);
  return *reinterpret_cast<unsigned short*>(&hb);
}

// ---------------- prep kernels ----------------
struct WPtrs { const float* w[5]; };

extern "C" __global__ void pack_big(WPtrs p, unsigned short* __restrict__ dst)
{
  int g = blockIdx.x * blockDim.x + threadIdx.x;  // 5*10*16*8*64 = 409600
  if (g >= 5 * HN * 16 * 8 * 64) return;
  int lane = g & 63; int t = g >> 6;
  int nt = t & 7; t >>= 3;
  int ks = t & 15; t >>= 4;
  int h = t % HN;
  int a = t / HN;
  const float* src = p.w[a] + (size_t)h * 65536
                   + (nt * 32 + (lane & 31)) * 256 + ks * 16 + (lane >> 5) * 8;
  unsigned short* d = dst + (size_t)a * WPK_ELEMS_PER_ARR + (size_t)h * WPK_ELEMS_PER_HEAD
                    + ((ks * 8 + nt) * 64 + lane) * 8;
  #pragma unroll
  for (int j = 0; j < 8; ++j) d[j] = f2bf(src[j]);
}

extern "C" __global__ void pack_w5(const float* __restrict__ w51, const float* __restrict__ w52,
                                   unsigned short* __restrict__ dst)
{
  int g = blockIdx.x * blockDim.x + threadIdx.x;  // 2*10*16*64 = 20480
  if (g >= 2 * HN * 16 * 64) return;
  int lane = g & 63; int t = g >> 6;
  int ks = t & 15; t >>= 4;
  int h = t % HN;
  int br = t / HN;
  const float* w = br ? w52 : w51;   // (10,2,256)
  int col = lane & 31;
  int k = ks * 16 + (lane >> 5) * 8;
  unsigned short* d = dst + ((size_t)(br * HN + h) * 16 + ks) * 512 + lane * 8;
  #pragma unroll
  for (int j = 0; j < 8; ++j) {
    float v = (col < 2) ? w[(size_t)h * 512 + col * 256 + k + j] : 0.f;
    d[j] = f2bf(v);
  }
}

// ---------------- fused main kernel ----------------

template<bool RELU>
__device__ __forceinline__ void gemm_layer(const char* sin_, char* sout,
                                           const unsigned short* __restrict__ wl,
                                           const float* __restrict__ bias,
                                           int lane, int wm, int wn)
{
  const int mbase = wm * 64;
  const int noff  = wn * 64;
  const int r31 = lane & 31, hi = lane >> 5;
  const int c0 = noff + r31;
  const int c1 = noff + 32 + r31;
  float bv0 = bias[c0], bv1 = bias[c1];
  f32x16_t acc[2][2];
  #pragma unroll
  for (int i = 0; i < 16; ++i) {
    acc[0][0][i] = bv0; acc[0][1][i] = bv1;
    acc[1][0][i] = bv0; acc[1][1][i] = bv1;
  }
  const bf16x8_t* wp = (const bf16x8_t*)wl;
  #pragma unroll
  for (int ks = 0; ks < 16; ++ks) {
    bf16x8_t a0 = *(const bf16x8_t*)(sin_ + swzoff(mbase + r31,      ks * 32 + hi * 16));
    bf16x8_t a1 = *(const bf16x8_t*)(sin_ + swzoff(mbase + 32 + r31, ks * 32 + hi * 16));
    bf16x8_t b0 = wp[(ks * 8 + wn * 2 + 0) * 64 + lane];
    bf16x8_t b1 = wp[(ks * 8 + wn * 2 + 1) * 64 + lane];
    acc[0][0] = __builtin_amdgcn_mfma_f32_32x32x16_bf16(a0, b0, acc[0][0], 0, 0, 0);
    acc[0][1] = __builtin_amdgcn_mfma_f32_32x32x16_bf16(a0, b1, acc[0][1], 0, 0, 0);
    acc[1][0] = __builtin_amdgcn_mfma_f32_32x32x16_bf16(a1, b0, acc[1][0], 0, 0, 0);
    acc[1][1] = __builtin_amdgcn_mfma_f32_32x32x16_bf16(a1, b1, acc[1][1], 0, 0, 0);
  }
  __syncthreads();   // all reads landed in acc -> in-place overwrite is safe
  #pragma unroll
  for (int mt = 0; mt < 2; ++mt) {
    #pragma unroll
    for (int nt = 0; nt < 2; ++nt) {
      int colb = (noff + nt * 32 + r31) * 2;
      #pragma unroll
      for (int r = 0; r < 16; ++r) {
        int row = mbase + mt * 32 + (r & 3) + 8 * (r >> 2) + 4 * hi;
        float v = acc[mt][nt][r];
        if (RELU) v = fmaxf(v, 0.f);
        *(unsigned short*)(sout + swzoff(row, colb)) = f2bf(v);
      }
    }
  }
  __syncthreads();
}

template<bool SIG>
__device__ __forceinline__ void final_layer(const char* sin_, float* sbuf,
                                            const unsigned short* __restrict__ w5,
                                            const float* __restrict__ b5,
                                            int lane, int wave)
{
  if (wave < 4) {
    const int mbase = wave * 32;
    const int r31 = lane & 31, hi = lane >> 5;
    float bv = (r31 < 2) ? b5[r31] : 0.f;
    f32x16_t acc;
    #pragma unroll
    for (int i = 0; i < 16; ++i) acc[i] = bv;
    const bf16x8_t* wp = (const bf16x8_t*)w5;
    #pragma unroll
    for (int ks = 0; ks < 16; ++ks) {
      bf16x8_t a = *(const bf16x8_t*)(sin_ + swzoff(mbase + r31, ks * 32 + hi * 16));
      bf16x8_t b = wp[ks * 64 + lane];
      acc = __builtin_amdgcn_mfma_f32_32x32x16_bf16(a, b, acc, 0, 0, 0);
    }
    if (r31 < 2) {
      #pragma unroll
      for (int r = 0; r < 16; ++r) {
        int row = mbase + (r & 3) + 8 * (r >> 2) + 4 * hi;
        float v = acc[r];
        if (SIG) v = 4.f / (1.f + __expf(-v));
        sbuf[row * 2 + r31] = v;
      }
    }
  }
  __syncthreads();
}

extern "C" __global__ __launch_bounds__(512, 2)
void abnet_main(const float* __restrict__ x, const float* __restrict__ wt,
                const float* __restrict__ mean, const float* __restrict__ stdv,
                const float* __restrict__ mlab, const float* __restrict__ slab,
                const float* __restrict__ W1, const float* __restrict__ b1,
                const float* __restrict__ b2, const float* __restrict__ b31,
                const float* __restrict__ b32, const float* __restrict__ b41,
                const float* __restrict__ b42, const float* __restrict__ b51,
                const float* __restrict__ b52,
                const unsigned short* __restrict__ wpk,
                const unsigned short* __restrict__ w5pk,
                float* __restrict__ out)
{
  extern __shared__ char smem[];
  char*  bufA = smem + OFF_BUFA;
  char*  bufB = smem + OFF_BUFB;
  float* s51  = (float*)(smem + OFF_S51);
  float* s52  = (float*)(smem + OFF_S52);
  float* w1s  = (float*)(smem + OFF_W1S);
  float* b1s  = (float*)(smem + OFF_B1S);

  const int tid  = threadIdx.x;
  const int lane = tid & 63, wave = tid >> 6;
  const int wm = wave >> 2, wn = wave & 3;
  const int row0 = blockIdx.x * MT;

  // ---- per-row CBF scalars (threads 0..127), all f32, kept in registers ----
  float e_bar = 0, e_bdot = 0, e_lf2b = 0, e_g1 = 0, e_g2 = 0, e_ggi = 0;
  float accu0 = 0.f, accu1 = 0.f, a0r = 0.f;
  float sm_m = 0.f, sm_inv = 0.f, ml0 = 0, ml1 = 0, isl0 = 1, isl1 = 1;
  if (tid < MT) {
    f32x4_t xr = *(const f32x4_t*)(x + (size_t)(row0 + tid) * 4);
    float t1  = xr[0] * stdv[0] + mean[0];
    float w1v = xr[1] * stdv[1] + mean[1];
    float t2  = xr[2] * stdv[2] + mean[2];
    float w2v = xr[3] * stdv[3] + mean[3];
    float s1, c1, s2, c2;
    sincosf(t1, &s1, &c1);
    sincosf(t2, &s2, &c2);
    float px = 3.f * c1 + 3.f * c2 - 0.f;          // OBS_X = 0
    float py = 3.f * s1 + 3.f * s2 - 7.f;          // OBS_Y = 7
    float vx = -3.f * s1 * w1v - 3.f * s2 * w2v;
    float vy =  3.f * c1 * w1v + 3.f * c2 * w2v;
    e_bar  = px * px + py * py - 16.f;             // R^2 = 16
    e_bdot = 2.f * (px * vx + py * vy);
    e_lf2b = 2.f * vx * vx + 2.f * vy * vy
           + 2.f * px * (-3.f * c1 * w1v * w1v - 3.f * c2 * w2v * w2v)
           + 2.f * py * (-3.f * s1 * w1v * w1v - 3.f * s2 * w2v * w2v);
    e_g1 = 6.f * (px * s1 - py * c1);              // -LgLfbu1
    e_g2 = 6.f * (px * s2 - py * c2);              // -LgLfbu2
    e_ggi = 1.f / (e_g1 * e_g1 + e_g2 * e_g2);
    // softmax(wt) pieces
    float m = wt[0];
    for (int i = 1; i < HN; ++i) m = fmaxf(m, wt[i]);
    float s = 0.f;
    for (int i = 0; i < HN; ++i) s += __expf(wt[i] - m);
    sm_m = m; sm_inv = 1.f / s;
    ml0 = mlab[0]; ml1 = mlab[1];
    isl0 = 1.f / slab[0]; isl1 = 1.f / slab[1];
  }

  // x row for layer-1 (invariant across heads)
  const int l1_r = tid >> 2, l1_q = tid & 3;
  f32x4_t xr_l1 = *(const f32x4_t*)(x + (size_t)(row0 + l1_r) * 4);

  for (int h = 0; h < HN; ++h) {
    // ---- stage W1[h], b1[h] into LDS ----
    for (int i = tid; i < 1024 + 256; i += 512) {
      if (i < 1024) w1s[i] = W1[(size_t)h * 1024 + i];
      else          b1s[i - 1024] = b1[(size_t)h * 256 + (i - 1024)];
    }
    __syncthreads();

    // ---- layer 1 (K=4, f32 VALU) -> bufA ----
    #pragma unroll
    for (int c8 = 0; c8 < 8; ++c8) {
      int cb = l1_q * 64 + c8 * 8;
      bf16x8_t pkt;
      #pragma unroll
      for (int j = 0; j < 8; ++j) {
        int c = cb + j;
        f32x4_t w = *(const f32x4_t*)(w1s + c * 4);
        float v = b1s[c] + xr_l1[0] * w[0] + xr_l1[1] * w[1]
                         + xr_l1[2] * w[2] + xr_l1[3] * w[3];
        v = fmaxf(v, 0.f);
        pkt[j] = (short)f2bf(v);
      }
      *(bf16x8_t*)(bufA + swzoff(l1_r, cb * 2)) = pkt;
    }
    __syncthreads();

    const unsigned short* wh = wpk + (size_t)h * WPK_ELEMS_PER_HEAD;
    gemm_layer<true>(bufA, bufB, wh + 0 * WPK_ELEMS_PER_ARR, b2  + h * DH, lane, wm, wn); // x2
    gemm_layer<true>(bufB, bufA, wh + 1 * WPK_ELEMS_PER_ARR, b31 + h * DH, lane, wm, wn); // x31
    gemm_layer<true>(bufA, bufA, wh + 3 * WPK_ELEMS_PER_ARR, b41 + h * DH, lane, wm, wn); // x41
    final_layer<false>(bufA, s51, w5pk + (size_t)(0 * HN + h) * W5PK_ELEMS_PER_BH,
                       b51 + h * 2, lane, wave);                                          // x51
    gemm_layer<true>(bufB, bufB, wh + 2 * WPK_ELEMS_PER_ARR, b32 + h * DH, lane, wm, wn); // x32
    gemm_layer<true>(bufB, bufB, wh + 4 * WPK_ELEMS_PER_ARR, b42 + h * DH, lane, wm, wn); // x42
    final_layer<true>(bufB, s52, w5pk + (size_t)(1 * HN + h) * W5PK_ELEMS_PER_BH,
                      b52 + h * 2, lane, wave);                                           // x52

    // ---- per-head CBF epilogue (f32) ----
    if (tid < MT) {
      float u1 = -s51[tid * 2 + 0];
      float u2 = -s51[tid * 2 + 1];
      float bi = s52[tid * 2 + 1];
      if (h == 0) a0r = s52[tid * 2 + 0];
      float hv   = e_lf2b + (a0r + bi) * e_bdot + a0r * bi * e_bar;
      float viol = u1 * e_g1 + u2 * e_g2 - hv;
      float lam  = fmaxf(viol, 0.f) * e_ggi;
      float uu1 = u1 - lam * e_g1;
      float uu2 = u2 - lam * e_g2;
      float whv = __expf(wt[h] - sm_m) * sm_inv;
      accu0 += whv * (uu1 - ml0) * isl0;
      accu1 += whv * (uu2 - ml1) * isl1;
    }
  }

  if (tid < MT) {
    float2 o; o.x = accu0; o.y = accu1;
    *(float2*)(out + (size_t)(row0 + tid) * 2) = o;
  }
}

// ---------------- launch ----------------
extern "C" void kernel_launch(void* const* d_in, const int* in_sizes, int n_in,
                              void* d_out, int out_size, void* d_ws, size_t ws_size,
                              hipStream_t stream)
{
  const float* x    = (const float*)d_in[0];
  // d_in[1] = sgn (unused by reference forward)
  const float* wt   = (const float*)d_in[2];
  const float* mean = (const float*)d_in[3];
  const float* stdv = (const float*)d_in[4];
  const float* mlab = (const float*)d_in[5];
  const float* slab = (const float*)d_in[6];
  const float* W1   = (const float*)d_in[7];
  const float* b1   = (const float*)d_in[8];
  WPtrs wp;
  wp.w[0] = (const float*)d_in[9];   // W2
  wp.w[1] = (const float*)d_in[11];  // W31
  wp.w[2] = (const float*)d_in[13];  // W32
  wp.w[3] = (const float*)d_in[15];  // W41
  wp.w[4] = (const float*)d_in[17];  // W42
  const float* b2  = (const float*)d_in[10];
  const float* b31 = (const float*)d_in[12];
  const float* b32 = (const float*)d_in[14];
  const float* b41 = (const float*)d_in[16];
  const float* b42 = (const float*)d_in[18];
  const float* W51 = (const float*)d_in[19];
  const float* b51 = (const float*)d_in[20];
  const float* W52 = (const float*)d_in[21];
  const float* b52 = (const float*)d_in[22];

  unsigned short* wpk  = (unsigned short*)d_ws;
  unsigned short* w5pk = (unsigned short*)((char*)d_ws + (size_t)5 * HN * DH * DH * 2);

  hipLaunchKernelGGL(pack_big, dim3(1600), dim3(256), 0, stream, wp, wpk);
  hipLaunchKernelGGL(pack_w5,  dim3(80),   dim3(256), 0, stream, W51, W52, w5pk);

  (void)hipFuncSetAttribute(reinterpret_cast<const void*>(abnet_main),
                            hipFuncAttributeMaxDynamicSharedMemorySize, SMEM_BYTES);
  hipLaunchKernelGGL(abnet_main, dim3(BN / MT), dim3(512), SMEM_BYTES, stream,
                     x, wt, mean, stdv, mlab, slab, W1, b1,
                     b2, b31, b32, b41, b42, b51, b52,
                     wpk, w5pk, (float*)d_out);
}

// Round 2
// 503.429 us; speedup vs baseline: 1.5127x; 1.5127x over previous
//
#include <hip/hip_runtime.h>
#include <hip/hip_bf16.h>

typedef __attribute__((ext_vector_type(8)))  short bf16x8_t;
typedef __attribute__((ext_vector_type(16))) float f32x16_t;
typedef __attribute__((ext_vector_type(4)))  float f32x4_t;

#define HN 10
#define BN 32768
#define DH 256
#define MT 64

// LDS layout (bytes)
#define SMEM_BYTES 71680
#define OFF_BUFA 0
#define OFF_BUFB 32768
#define OFF_S51  65536
#define OFF_S52  66048
#define OFF_W1S  66560
#define OFF_B1S  70656

// ws layout: packed bf16 weights
// wpk: [5 layer-arrays][10 heads][ks(16)][ntile(8)][lane(64)][8]  (65536 bf16 per (arr,head))
// w5pk: [2 branches][10 heads][ks(16)][lane(64)][8]               (8192 bf16 per (br,head))
#define WPK_ELEMS_PER_HEAD (DH*DH)
#define WPK_ELEMS_PER_ARR  (HN*DH*DH)
#define W5PK_ELEMS_PER_BH  8192

__device__ __forceinline__ unsigned swzoff(int row, int colb) {
  // row-major [64][256] bf16, 512 B/row; XOR row bits 0-3 into byte-offset
  // bits 4-7: a-fragment read (32 rows, same col) spreads over 16 16B slots
  // -> 2 lanes/slot = conflict-free (2-way is free per m136).
  return (unsigned)(row * 512 + (colb ^ ((row & 15) << 4)));
}

__device__ __forceinline__ unsigned short f2bf(float v) {
  __hip_bfloat16 hb = __float2bfloat16(v);
  return *reinterpret_cast<unsigned short*>(&hb);
}

// ---------------- prep kernels (unchanged, layout verified in R1) ----------------
struct WPtrs { const float* w[5]; };

extern "C" __global__ void pack_big(WPtrs p, unsigned short* __restrict__ dst)
{
  int g = blockIdx.x * blockDim.x + threadIdx.x;  // 5*10*16*8*64 = 409600
  if (g >= 5 * HN * 16 * 8 * 64) return;
  int lane = g & 63; int t = g >> 6;
  int nt = t & 7; t >>= 3;
  int ks = t & 15; t >>= 4;
  int h = t % HN;
  int a = t / HN;
  const float* src = p.w[a] + (size_t)h * 65536
                   + (nt * 32 + (lane & 31)) * 256 + ks * 16 + (lane >> 5) * 8;
  unsigned short* d = dst + (size_t)a * WPK_ELEMS_PER_ARR + (size_t)h * WPK_ELEMS_PER_HEAD
                    + ((ks * 8 + nt) * 64 + lane) * 8;
  #pragma unroll
  for (int j = 0; j < 8; ++j) d[j] = f2bf(src[j]);
}

extern "C" __global__ void pack_w5(const float* __restrict__ w51, const float* __restrict__ w52,
                                   unsigned short* __restrict__ dst)
{
  int g = blockIdx.x * blockDim.x + threadIdx.x;  // 2*10*16*64 = 20480
  if (g >= 2 * HN * 16 * 64) return;
  int lane = g & 63; int t = g >> 6;
  int ks = t & 15; t >>= 4;
  int h = t % HN;
  int br = t / HN;
  const float* w = br ? w52 : w51;   // (10,2,256)
  int col = lane & 31;
  int k = ks * 16 + (lane >> 5) * 8;
  unsigned short* d = dst + ((size_t)(br * HN + h) * 16 + ks) * 512 + lane * 8;
  #pragma unroll
  for (int j = 0; j < 8; ++j) {
    float v = (col < 2) ? w[(size_t)h * 512 + col * 256 + k + j] : 0.f;
    d[j] = f2bf(v);
  }
}

// ---------------- fused main kernel ----------------

// Wave tile: 32 rows x 64 cols (wm = wave>>2 in [0,2), wn = wave&3 in [0,4)).
// Per ks: 1 LDS a-frag read + 2 global b-frag loads + 2 MFMAs.
template<bool RELU, bool INPLACE>
__device__ __forceinline__ void gemm_layer(const char* sin_, char* sout,
                                           const unsigned short* __restrict__ wl,
                                           const float* __restrict__ bias,
                                           int lane, int wm, int wn)
{
  const int mbase = wm * 32;
  const int noff  = wn * 64;
  const int r31 = lane & 31, hi = lane >> 5;
  float bv0 = bias[noff + r31], bv1 = bias[noff + 32 + r31];
  f32x16_t acc[2];
  #pragma unroll
  for (int i = 0; i < 16; ++i) { acc[0][i] = bv0; acc[1][i] = bv1; }

  const bf16x8_t* wp0 = (const bf16x8_t*)wl + (wn * 2) * 64 + lane;
  bf16x8_t b0 = wp0[0], b1 = wp0[64];          // ks stride = 8*64 = 512 frags
  #pragma unroll
  for (int ks = 0; ks < 16; ++ks) {
    bf16x8_t nb0, nb1;
    if (ks < 15) { nb0 = wp0[(ks + 1) * 512]; nb1 = wp0[(ks + 1) * 512 + 64]; }
    bf16x8_t a = *(const bf16x8_t*)(sin_ + swzoff(mbase + r31, ks * 32 + hi * 16));
    acc[0] = __builtin_amdgcn_mfma_f32_32x32x16_bf16(a, b0, acc[0], 0, 0, 0);
    acc[1] = __builtin_amdgcn_mfma_f32_32x32x16_bf16(a, b1, acc[1], 0, 0, 0);
    b0 = nb0; b1 = nb1;
  }
  if (INPLACE) __syncthreads();   // reads landed in acc -> safe to overwrite
  #pragma unroll
  for (int nt = 0; nt < 2; ++nt) {
    int colb = (noff + nt * 32 + r31) * 2;
    #pragma unroll
    for (int r = 0; r < 16; ++r) {
      int row = mbase + (r & 3) + 8 * (r >> 2) + 4 * hi;
      float v = acc[nt][r];
      if (RELU) v = fmaxf(v, 0.f);
      *(unsigned short*)(sout + swzoff(row, colb)) = f2bf(v);
    }
  }
  __syncthreads();
}

template<bool SIG>
__device__ __forceinline__ void final_layer(const char* sin_, float* sbuf,
                                            const unsigned short* __restrict__ w5,
                                            const float* __restrict__ b5,
                                            int lane, int wave)
{
  if (wave < 2) {
    const int mbase = wave * 32;
    const int r31 = lane & 31, hi = lane >> 5;
    float bv = (r31 < 2) ? b5[r31] : 0.f;
    f32x16_t acc;
    #pragma unroll
    for (int i = 0; i < 16; ++i) acc[i] = bv;
    const bf16x8_t* wp = (const bf16x8_t*)w5;
    #pragma unroll
    for (int ks = 0; ks < 16; ++ks) {
      bf16x8_t a = *(const bf16x8_t*)(sin_ + swzoff(mbase + r31, ks * 32 + hi * 16));
      bf16x8_t b = wp[ks * 64 + lane];
      acc = __builtin_amdgcn_mfma_f32_32x32x16_bf16(a, b, acc, 0, 0, 0);
    }
    if (r31 < 2) {
      #pragma unroll
      for (int r = 0; r < 16; ++r) {
        int row = mbase + (r & 3) + 8 * (r >> 2) + 4 * hi;
        float v = acc[r];
        if (SIG) v = 4.f / (1.f + __expf(-v));
        sbuf[row * 2 + r31] = v;
      }
    }
  }
  __syncthreads();
}

extern "C" __global__ __launch_bounds__(512, 4)
void abnet_main(const float* __restrict__ x, const float* __restrict__ wt,
                const float* __restrict__ mean, const float* __restrict__ stdv,
                const float* __restrict__ mlab, const float* __restrict__ slab,
                const float* __restrict__ W1, const float* __restrict__ b1,
                const float* __restrict__ b2, const float* __restrict__ b31,
                const float* __restrict__ b32, const float* __restrict__ b41,
                const float* __restrict__ b42, const float* __restrict__ b51,
                const float* __restrict__ b52,
                const unsigned short* __restrict__ wpk,
                const unsigned short* __restrict__ w5pk,
                float* __restrict__ out)
{
  extern __shared__ char smem[];
  char*  bufA = smem + OFF_BUFA;
  char*  bufB = smem + OFF_BUFB;
  float* s51  = (float*)(smem + OFF_S51);
  float* s52  = (float*)(smem + OFF_S52);
  float* w1s  = (float*)(smem + OFF_W1S);
  float* b1s  = (float*)(smem + OFF_B1S);

  const int tid  = threadIdx.x;
  const int lane = tid & 63, wave = tid >> 6;
  const int wm = wave >> 2, wn = wave & 3;
  const int row0 = blockIdx.x * MT;

  // ---- per-row CBF scalars (threads 0..63), all f32, kept in registers ----
  float e_bar = 0, e_bdot = 0, e_lf2b = 0, e_g1 = 0, e_g2 = 0, e_ggi = 0;
  float accu0 = 0.f, accu1 = 0.f, a0r = 0.f;
  float sm_m = 0.f, sm_inv = 0.f, ml0 = 0, ml1 = 0, isl0 = 1, isl1 = 1;
  if (tid < MT) {
    f32x4_t xr = *(const f32x4_t*)(x + (size_t)(row0 + tid) * 4);
    float t1  = xr[0] * stdv[0] + mean[0];
    float w1v = xr[1] * stdv[1] + mean[1];
    float t2  = xr[2] * stdv[2] + mean[2];
    float w2v = xr[3] * stdv[3] + mean[3];
    float s1, c1, s2, c2;
    sincosf(t1, &s1, &c1);
    sincosf(t2, &s2, &c2);
    float px = 3.f * c1 + 3.f * c2 - 0.f;          // OBS_X = 0
    float py = 3.f * s1 + 3.f * s2 - 7.f;          // OBS_Y = 7
    float vx = -3.f * s1 * w1v - 3.f * s2 * w2v;
    float vy =  3.f * c1 * w1v + 3.f * c2 * w2v;
    e_bar  = px * px + py * py - 16.f;             // R^2 = 16
    e_bdot = 2.f * (px * vx + py * vy);
    e_lf2b = 2.f * vx * vx + 2.f * vy * vy
           + 2.f * px * (-3.f * c1 * w1v * w1v - 3.f * c2 * w2v * w2v)
           + 2.f * py * (-3.f * s1 * w1v * w1v - 3.f * s2 * w2v * w2v);
    e_g1 = 6.f * (px * s1 - py * c1);              // -LgLfbu1
    e_g2 = 6.f * (px * s2 - py * c2);              // -LgLfbu2
    e_ggi = 1.f / (e_g1 * e_g1 + e_g2 * e_g2);
    float m = wt[0];
    for (int i = 1; i < HN; ++i) m = fmaxf(m, wt[i]);
    float s = 0.f;
    for (int i = 0; i < HN; ++i) s += __expf(wt[i] - m);
    sm_m = m; sm_inv = 1.f / s;
    ml0 = mlab[0]; ml1 = mlab[1];
    isl0 = 1.f / slab[0]; isl1 = 1.f / slab[1];
  }

  // x row for layer-1 (invariant across heads): thread -> (row = tid>>3, 32 cols)
  const int l1_r = tid >> 3, l1_q = tid & 7;
  f32x4_t xr_l1 = *(const f32x4_t*)(x + (size_t)(row0 + l1_r) * 4);

  for (int h = 0; h < HN; ++h) {
    // ---- stage W1[h], b1[h] into LDS ----
    for (int i = tid; i < 1024 + 256; i += 512) {
      if (i < 1024) w1s[i] = W1[(size_t)h * 1024 + i];
      else          b1s[i - 1024] = b1[(size_t)h * 256 + (i - 1024)];
    }
    __syncthreads();

    // ---- layer 1 (K=4, f32 VALU) -> bufA ----
    #pragma unroll
    for (int c8 = 0; c8 < 4; ++c8) {
      int cb = l1_q * 32 + c8 * 8;
      bf16x8_t pkt;
      #pragma unroll
      for (int j = 0; j < 8; ++j) {
        int c = cb + j;
        f32x4_t w = *(const f32x4_t*)(w1s + c * 4);
        float v = b1s[c] + xr_l1[0] * w[0] + xr_l1[1] * w[1]
                         + xr_l1[2] * w[2] + xr_l1[3] * w[3];
        v = fmaxf(v, 0.f);
        pkt[j] = (short)f2bf(v);
      }
      *(bf16x8_t*)(bufA + swzoff(l1_r, cb * 2)) = pkt;
    }
    __syncthreads();

    const unsigned short* wh = wpk + (size_t)h * WPK_ELEMS_PER_HEAD;
    gemm_layer<true,false>(bufA, bufB, wh + 0 * WPK_ELEMS_PER_ARR, b2  + h * DH, lane, wm, wn); // x2:  A->B
    gemm_layer<true,false>(bufB, bufA, wh + 1 * WPK_ELEMS_PER_ARR, b31 + h * DH, lane, wm, wn); // x31: B->A
    gemm_layer<true,true >(bufA, bufA, wh + 3 * WPK_ELEMS_PER_ARR, b41 + h * DH, lane, wm, wn); // x41: A->A
    final_layer<false>(bufA, s51, w5pk + (size_t)(0 * HN + h) * W5PK_ELEMS_PER_BH,
                       b51 + h * 2, lane, wave);                                                // x51
    gemm_layer<true,true >(bufB, bufB, wh + 2 * WPK_ELEMS_PER_ARR, b32 + h * DH, lane, wm, wn); // x32: B->B
    gemm_layer<true,true >(bufB, bufB, wh + 4 * WPK_ELEMS_PER_ARR, b42 + h * DH, lane, wm, wn); // x42: B->B
    final_layer<true>(bufB, s52, w5pk + (size_t)(1 * HN + h) * W5PK_ELEMS_PER_BH,
                      b52 + h * 2, lane, wave);                                                 // x52

    // ---- per-head CBF epilogue (f32) ----
    if (tid < MT) {
      float u1 = -s51[tid * 2 + 0];
      float u2 = -s51[tid * 2 + 1];
      float bi = s52[tid * 2 + 1];
      if (h == 0) a0r = s52[tid * 2 + 0];
      float hv   = e_lf2b + (a0r + bi) * e_bdot + a0r * bi * e_bar;
      float viol = u1 * e_g1 + u2 * e_g2 - hv;
      float lam  = fmaxf(viol, 0.f) * e_ggi;
      float uu1 = u1 - lam * e_g1;
      float uu2 = u2 - lam * e_g2;
      float whv = __expf(wt[h] - sm_m) * sm_inv;
      accu0 += whv * (uu1 - ml0) * isl0;
      accu1 += whv * (uu2 - ml1) * isl1;
    }
  }

  if (tid < MT) {
    float2 o; o.x = accu0; o.y = accu1;
    *(float2*)(out + (size_t)(row0 + tid) * 2) = o;
  }
}

// ---------------- launch ----------------
extern "C" void kernel_launch(void* const* d_in, const int* in_sizes, int n_in,
                              void* d_out, int out_size, void* d_ws, size_t ws_size,
                              hipStream_t stream)
{
  const float* x    = (const float*)d_in[0];
  // d_in[1] = sgn (unused by reference forward)
  const float* wt   = (const float*)d_in[2];
  const float* mean = (const float*)d_in[3];
  const float* stdv = (const float*)d_in[4];
  const float* mlab = (const float*)d_in[5];
  const float* slab = (const float*)d_in[6];
  const float* W1   = (const float*)d_in[7];
  const float* b1   = (const float*)d_in[8];
  WPtrs wp;
  wp.w[0] = (const float*)d_in[9];   // W2
  wp.w[1] = (const float*)d_in[11];  // W31
  wp.w[2] = (const float*)d_in[13];  // W32
  wp.w[3] = (const float*)d_in[15];  // W41
  wp.w[4] = (const float*)d_in[17];  // W42
  const float* b2  = (const float*)d_in[10];
  const float* b31 = (const float*)d_in[12];
  const float* b32 = (const float*)d_in[14];
  const float* b41 = (const float*)d_in[16];
  const float* b42 = (const float*)d_in[18];
  const float* W51 = (const float*)d_in[19];
  const float* b51 = (const float*)d_in[20];
  const float* W52 = (const float*)d_in[21];
  const float* b52 = (const float*)d_in[22];

  unsigned short* wpk  = (unsigned short*)d_ws;
  unsigned short* w5pk = (unsigned short*)((char*)d_ws + (size_t)5 * HN * DH * DH * 2);

  hipLaunchKernelGGL(pack_big, dim3(1600), dim3(256), 0, stream, wp, wpk);
  hipLaunchKernelGGL(pack_w5,  dim3(80),   dim3(256), 0, stream, W51, W52, w5pk);

  (void)hipFuncSetAttribute(reinterpret_cast<const void*>(abnet_main),
                            hipFuncAttributeMaxDynamicSharedMemorySize, SMEM_BYTES);
  hipLaunchKernelGGL(abnet_main, dim3(BN / MT), dim3(512), SMEM_BYTES, stream,
                     x, wt, mean, stdv, mlab, slab, W1, b1,
                     b2, b31, b32, b41, b42, b51, b52,
                     wpk, w5pk, (float*)d_out);
}